// Round 2
// baseline (689.164 us; speedup 1.0000x reference)
//
#include <hip/hip_runtime.h>
#include <hip/hip_bf16.h>
#include <stdint.h>
#include <stddef.h>

using bf16 = __hip_bfloat16;
using frag_ab = __attribute__((ext_vector_type(8))) short;  // 8 bf16 (4 VGPRs)
using frag_cd = __attribute__((ext_vector_type(4))) float;  // 4 fp32 acc

constexpr int BM = 128, BN = 128, BK = 32;

// C = A @ B^T   (A: MxK row-major bf16, B: NxK row-major bf16)
// EPI: 0 = fp32 C, 1 = split bf16 hi/lo, 2 = bf16
// SPLIT3: K-loop runs 3 phases over [Ahi|Alo|Ahi] x [Bhi|Bhi|Blo] (total 3K)
// CAUSAL: skip output blocks with col-block > row-block (square M==N grids)
// KCAUSAL: K-loop limited to (by+1)*BM (for attn@x where A rows are causal)
template <int EPI, bool SPLIT3, bool CAUSAL, bool KCAUSAL>
__global__ __launch_bounds__(256) void gemm_bt(
    const bf16* __restrict__ Ahi, const bf16* __restrict__ Alo,
    const bf16* __restrict__ Bhi, const bf16* __restrict__ Blo,
    float* __restrict__ Cf, bf16* __restrict__ Co, bf16* __restrict__ Clo,
    int M, int N, int K)
{
    const int bx = blockIdx.x;  // N tile
    const int by = blockIdx.y;  // M tile
    if (CAUSAL && bx > by) return;

    const int tid   = threadIdx.x;
    const int lane  = tid & 63;
    const int wave  = tid >> 6;
    const int wm    = wave >> 1;   // 0..1
    const int wn    = wave & 1;    // 0..1
    const int lrow  = lane & 15;   // tile row (A) / col (B,D)
    const int lquad = lane >> 4;   // 0..3

    __shared__ bf16 sA[BM * BK];   // 8 KB
    __shared__ bf16 sB[BN * BK];   // 8 KB

    const int row0 = by * BM;
    const int col0 = bx * BN;

    // staging: thread t, round r handles tile row (t>>2)+64r, cols (t&3)*8..+7
    const int srow = tid >> 2;
    const int scol = (tid & 3) * 8;

    frag_cd acc[4][4];
    const frag_cd fzero = {0.f, 0.f, 0.f, 0.f};
    #pragma unroll
    for (int i = 0; i < 4; ++i)
        #pragma unroll
        for (int j = 0; j < 4; ++j) acc[i][j] = fzero;

    const int Ktot = SPLIT3 ? 3 * K : (KCAUSAL ? (by + 1) * BM : K);

    for (int k0 = 0; k0 < Ktot; k0 += BK) {
        // phase select (wave-uniform)
        const bf16* Ap; const bf16* Bp; int kl;
        if (SPLIT3) {
            if (k0 < K)          { Ap = Ahi; Bp = Bhi; kl = k0; }
            else if (k0 < 2 * K) { Ap = Alo; Bp = Bhi; kl = k0 - K; }
            else                 { Ap = Ahi; Bp = Blo; kl = k0 - 2 * K; }
        } else { Ap = Ahi; Bp = Bhi; kl = k0; }

        __syncthreads();
        #pragma unroll
        for (int r = 0; r < 2; ++r) {
            const int trow = srow + 64 * r;
            *reinterpret_cast<uint4*>(&sA[trow * BK + scol]) =
                *reinterpret_cast<const uint4*>(&Ap[(size_t)(row0 + trow) * K + kl + scol]);
            *reinterpret_cast<uint4*>(&sB[trow * BK + scol]) =
                *reinterpret_cast<const uint4*>(&Bp[(size_t)(col0 + trow) * K + kl + scol]);
        }
        __syncthreads();

        frag_ab av[4], bv[4];
        #pragma unroll
        for (int mi = 0; mi < 4; ++mi)
            av[mi] = *reinterpret_cast<const frag_ab*>(
                &sA[(wm * 64 + mi * 16 + lrow) * BK + lquad * 8]);
        #pragma unroll
        for (int ni = 0; ni < 4; ++ni)
            bv[ni] = *reinterpret_cast<const frag_ab*>(
                &sB[(wn * 64 + ni * 16 + lrow) * BK + lquad * 8]);

        #pragma unroll
        for (int mi = 0; mi < 4; ++mi)
            #pragma unroll
            for (int ni = 0; ni < 4; ++ni)
                acc[mi][ni] = __builtin_amdgcn_mfma_f32_16x16x32_bf16(
                    av[mi], bv[ni], acc[mi][ni], 0, 0, 0);
    }

    // epilogue: D element (row = lquad*4 + r, col = lrow) within each 16x16 tile
    #pragma unroll
    for (int mi = 0; mi < 4; ++mi) {
        #pragma unroll
        for (int ni = 0; ni < 4; ++ni) {
            #pragma unroll
            for (int r = 0; r < 4; ++r) {
                const int row = row0 + wm * 64 + mi * 16 + lquad * 4 + r;
                const int col = col0 + wn * 64 + ni * 16 + lrow;
                const size_t idx = (size_t)row * N + col;
                const float v = acc[mi][ni][r];
                if (EPI == 0) {
                    Cf[idx] = v;
                } else if (EPI == 1) {
                    const bf16 h = (bf16)v;
                    Co[idx]  = h;
                    Clo[idx] = (bf16)(v - (float)h);
                } else {
                    Co[idx] = (bf16)v;
                }
            }
        }
    }
}

// fp32 -> bf16 hi (+ optional lo residual), 4 elems/thread
__global__ __launch_bounds__(256) void split_fp32(
    const float* __restrict__ in, bf16* __restrict__ hi, bf16* __restrict__ lo,
    size_t nelem)
{
    const size_t i = ((size_t)blockIdx.x * 256 + threadIdx.x) * 4;
    if (i >= nelem) return;
    const float4 v = *reinterpret_cast<const float4*>(in + i);
    union { bf16 b[4]; ushort4 u; } H, L;
    H.b[0] = (bf16)v.x; H.b[1] = (bf16)v.y; H.b[2] = (bf16)v.z; H.b[3] = (bf16)v.w;
    *reinterpret_cast<ushort4*>(hi + i) = H.u;
    if (lo) {
        L.b[0] = (bf16)(v.x - (float)H.b[0]);
        L.b[1] = (bf16)(v.y - (float)H.b[1]);
        L.b[2] = (bf16)(v.z - (float)H.b[2]);
        L.b[3] = (bf16)(v.w - (float)H.b[3]);
        *reinterpret_cast<ushort4*>(lo + i) = L.u;
    }
}

// row-wise causal softmax: P[row, 0..row] = softmax(S[row, 0..row]), zeros to
// the 128-padded row end (so the causal-K GEMM can read full 128-blocks).
__global__ __launch_bounds__(256) void softmax_rows(
    const float* __restrict__ S, bf16* __restrict__ P, int n)
{
    const int row = blockIdx.x;
    const int len = row + 1;
    const int padlen = ((row >> 7) + 1) << 7;
    const float* srow = S + (size_t)row * n;
    bf16* prow = P + (size_t)row * n;
    const int tid = threadIdx.x;
    const int lane = tid & 63, wave = tid >> 6;
    __shared__ float red[4];

    float m = -3.0e38f;
    for (int j = tid; j < len; j += 256) m = fmaxf(m, srow[j]);
    #pragma unroll
    for (int off = 32; off; off >>= 1) m = fmaxf(m, __shfl_xor(m, off, 64));
    if (lane == 0) red[wave] = m;
    __syncthreads();
    m = fmaxf(fmaxf(red[0], red[1]), fmaxf(red[2], red[3]));
    __syncthreads();

    float s = 0.f;
    for (int j = tid; j < len; j += 256) s += __expf(srow[j] - m);
    #pragma unroll
    for (int off = 32; off; off >>= 1) s += __shfl_xor(s, off, 64);
    if (lane == 0) red[wave] = s;
    __syncthreads();
    s = red[0] + red[1] + red[2] + red[3];
    const float inv = 1.0f / s;

    const bf16 z = (bf16)0.0f;
    for (int j = tid; j < padlen; j += 256)
        prow[j] = (j < len) ? (bf16)(__expf(srow[j] - m) * inv) : z;
}

// out[c*rows + r] = (bf16)in[r*cols + c]   (fp32 in, bf16 out)
__global__ __launch_bounds__(256) void transpose_f32_bf16(
    const float* __restrict__ in, bf16* __restrict__ out, int rows, int cols)
{
    __shared__ float tile[32][33];
    const int bx = blockIdx.x;  // col tile
    const int by = blockIdx.y;  // row tile
    const int tx = threadIdx.x & 31;
    const int ty = threadIdx.x >> 5;  // 0..7
    #pragma unroll
    for (int r = 0; r < 4; ++r)
        tile[ty + 8 * r][tx] = in[(size_t)(by * 32 + ty + 8 * r) * cols + bx * 32 + tx];
    __syncthreads();
    #pragma unroll
    for (int r = 0; r < 4; ++r)
        out[(size_t)(bx * 32 + ty + 8 * r) * rows + by * 32 + tx] =
            (bf16)tile[tx][ty + 8 * r];
}

extern "C" void kernel_launch(void* const* d_in, const int* in_sizes, int n_in,
                              void* d_out, int out_size, void* d_ws, size_t ws_size,
                              hipStream_t stream)
{
    const int n = 4096, d = 2048;
    const float* x   = (const float*)d_in[0];
    const float* Wqk = (const float*)d_in[1];
    const float* Wov = (const float*)d_in[2];
    float* out = (float*)d_out;

    char* ws = (char*)d_ws;
    const size_t MB = 1 << 20;
    bf16*  xhi  = (bf16*)(ws);              // 16 MB  (n x d)
    bf16*  xlo  = (bf16*)(ws + 16  * MB);   // 16 MB
    bf16*  Whi  = (bf16*)(ws + 32  * MB);   //  8 MB  (d x d)
    bf16*  Wlo  = (bf16*)(ws + 40  * MB);   //  8 MB
    bf16*  Wov_h= (bf16*)(ws + 48  * MB);   //  8 MB
    bf16*  xT   = (bf16*)(ws + 56  * MB);   // 16 MB  (d x n)
    bf16*  qhi  = (bf16*)(ws + 72  * MB);   // 16 MB  (n x d)
    bf16*  qlo  = (bf16*)(ws + 88  * MB);   // 16 MB
    float* S    = (float*)(ws + 104 * MB);  // 64 MB  (n x n)  -> peak 168 MB
    bf16*  P    = (bf16*)(ws);              // 32 MB  (n x n), reuses xhi+xlo (dead)
    bf16*  o    = (bf16*)(ws + 32  * MB);   // 16 MB  (n x d), reuses Whi+Wlo (dead)

    const dim3 blk(256);

    // input fp32 -> bf16 hi/lo
    split_fp32<<<dim3((n * d) / (256 * 4)), blk, 0, stream>>>(x,   xhi, xlo, (size_t)n * d);
    split_fp32<<<dim3((d * d) / (256 * 4)), blk, 0, stream>>>(Wqk, Whi, Wlo, (size_t)d * d);
    split_fp32<<<dim3((d * d) / (256 * 4)), blk, 0, stream>>>(Wov, Wov_h, nullptr, (size_t)d * d);
    transpose_f32_bf16<<<dim3(d / 32, n / 32), blk, 0, stream>>>(x, xT, n, d);

    // q = x @ Wqk^T in split precision (3-phase), output split hi/lo
    gemm_bt<1, true, false, false><<<dim3(d / BN, n / BM), blk, 0, stream>>>(
        xhi, xlo, Whi, Wlo, nullptr, qhi, qlo, n, d, d);

    // S = q @ x^T in split precision (3-phase), lower-triangular blocks, fp32
    gemm_bt<0, true, true, false><<<dim3(n / BN, n / BM), blk, 0, stream>>>(
        qhi, qlo, xhi, xlo, S, nullptr, nullptr, n, n, d);

    // P = causal row softmax(S), bf16, zero-padded to 128 boundary
    softmax_rows<<<dim3(n), blk, 0, stream>>>(S, P, n);

    // o = P @ x = P @ xT^T  (K limited causally per row-block), bf16
    gemm_bt<2, false, false, true><<<dim3(d / BN, n / BM), blk, 0, stream>>>(
        P, nullptr, xT, nullptr, nullptr, o, nullptr, n, d, n);

    // out = o @ Wov^T, fp32 to d_out
    gemm_bt<0, false, false, false><<<dim3(d / BN, n / BM), blk, 0, stream>>>(
        o, nullptr, Wov_h, nullptr, out, nullptr, nullptr, n, d, d);
}

// Round 3
// 655.152 us; speedup vs baseline: 1.0519x; 1.0519x over previous
//
#include <hip/hip_runtime.h>
#include <hip/hip_bf16.h>
#include <stdint.h>
#include <stddef.h>

using bf16 = __hip_bfloat16;
using frag_ab = __attribute__((ext_vector_type(8))) short;  // 8 bf16 (4 VGPRs)
using frag_cd = __attribute__((ext_vector_type(4))) float;  // 4 fp32 acc

constexpr int BM = 128, BN = 128, BK = 32;

// async global->LDS DMA, 16 B/lane; LDS dest = wave-uniform base + lane*16
#define GLOAD_LDS16(gp, lp)                                        \
    __builtin_amdgcn_global_load_lds(                              \
        (const __attribute__((address_space(1))) unsigned int*)(gp),\
        (__attribute__((address_space(3))) unsigned int*)(lp), 16, 0, 0)

// C = A @ B^T   (A: MxK row-major bf16, B: NxK row-major bf16)
// EPI: 0 = fp32 C, 1 = split bf16 hi/lo, 2 = bf16
// SPLIT3: K-loop runs 3 phases over [Ahi|Alo|Ahi] x [Bhi|Bhi|Blo] (total 3K)
// CAUSAL: skip output blocks with col-block > row-block (square M==N grids)
// KCAUSAL: K-loop limited to (by+1)*BM (for attn@x where A rows are causal)
template <int EPI, bool SPLIT3, bool CAUSAL, bool KCAUSAL>
__global__ __launch_bounds__(256) void gemm_bt(
    const bf16* __restrict__ Ahi, const bf16* __restrict__ Alo,
    const bf16* __restrict__ Bhi, const bf16* __restrict__ Blo,
    float* __restrict__ Cf, bf16* __restrict__ Co, bf16* __restrict__ Clo,
    int M, int N, int K)
{
    const int bx = blockIdx.x;  // N tile
    const int by = blockIdx.y;  // M tile
    if (CAUSAL && bx > by) return;

    const int tid   = threadIdx.x;
    const int lane  = tid & 63;
    const int wave  = tid >> 6;
    const int wm    = wave >> 1;   // 0..1
    const int wn    = wave & 1;    // 0..1
    const int lrow  = lane & 15;   // tile row (A) / col (B,D)
    const int lquad = lane >> 4;   // 0..3

    __shared__ bf16 sA[BM * BK];   // 8 KB, thread t owns bytes [t*16, t*16+16) (+r*4096)
    __shared__ bf16 sB[BN * BK];   // 8 KB

    const int row0 = by * BM;
    const int col0 = bx * BN;

    // staging: thread t, round r covers tile row (t>>2)+64r, cols (t&3)*8..+7
    const int srow = tid >> 2;
    const int scol = (tid & 3) * 8;
    // wave-uniform LDS bases (elements): wave*512 + r*2048  <=> bytes wave*1024 + r*4096
    bf16* const lA0 = &sA[wave * 512];
    bf16* const lB0 = &sB[wave * 512];

    frag_cd acc[4][4];
    const frag_cd fzero = {0.f, 0.f, 0.f, 0.f};
    #pragma unroll
    for (int i = 0; i < 4; ++i)
        #pragma unroll
        for (int j = 0; j < 4; ++j) acc[i][j] = fzero;

    const int Ktot = SPLIT3 ? 3 * K : (KCAUSAL ? (by + 1) * BM : K);

    for (int k0 = 0; k0 < Ktot; k0 += BK) {
        // phase select (wave-uniform)
        const bf16* Ap; const bf16* Bp; int kl;
        if (SPLIT3) {
            if (k0 < K)          { Ap = Ahi; Bp = Bhi; kl = k0; }
            else if (k0 < 2 * K) { Ap = Alo; Bp = Bhi; kl = k0 - K; }
            else                 { Ap = Ahi; Bp = Blo; kl = k0 - 2 * K; }
        } else { Ap = Ahi; Bp = Bhi; kl = k0; }

        __syncthreads();
        #pragma unroll
        for (int r = 0; r < 2; ++r) {
            const int trow = srow + 64 * r;
            GLOAD_LDS16(&Ap[(size_t)(row0 + trow) * K + kl + scol], lA0 + r * 2048);
            GLOAD_LDS16(&Bp[(size_t)(col0 + trow) * K + kl + scol], lB0 + r * 2048);
        }
        __syncthreads();

        frag_ab av[4], bv[4];
        #pragma unroll
        for (int mi = 0; mi < 4; ++mi)
            av[mi] = *reinterpret_cast<const frag_ab*>(
                &sA[(wm * 64 + mi * 16 + lrow) * BK + lquad * 8]);
        #pragma unroll
        for (int ni = 0; ni < 4; ++ni)
            bv[ni] = *reinterpret_cast<const frag_ab*>(
                &sB[(wn * 64 + ni * 16 + lrow) * BK + lquad * 8]);

        #pragma unroll
        for (int mi = 0; mi < 4; ++mi)
            #pragma unroll
            for (int ni = 0; ni < 4; ++ni)
                acc[mi][ni] = __builtin_amdgcn_mfma_f32_16x16x32_bf16(
                    av[mi], bv[ni], acc[mi][ni], 0, 0, 0);
    }

    // epilogue: D element (row = lquad*4 + r, col = lrow) within each 16x16 tile
    #pragma unroll
    for (int mi = 0; mi < 4; ++mi) {
        #pragma unroll
        for (int ni = 0; ni < 4; ++ni) {
            #pragma unroll
            for (int r = 0; r < 4; ++r) {
                const int row = row0 + wm * 64 + mi * 16 + lquad * 4 + r;
                const int col = col0 + wn * 64 + ni * 16 + lrow;
                const size_t idx = (size_t)row * N + col;
                const float v = acc[mi][ni][r];
                if (EPI == 0) {
                    Cf[idx] = v;
                } else if (EPI == 1) {
                    const bf16 h = (bf16)v;
                    Co[idx]  = h;
                    Clo[idx] = (bf16)(v - (float)h);
                } else {
                    Co[idx] = (bf16)v;
                }
            }
        }
    }
}

// fp32 -> bf16 hi (+ optional lo residual), 4 elems/thread
__global__ __launch_bounds__(256) void split_fp32(
    const float* __restrict__ in, bf16* __restrict__ hi, bf16* __restrict__ lo,
    size_t nelem)
{
    const size_t i = ((size_t)blockIdx.x * 256 + threadIdx.x) * 4;
    if (i >= nelem) return;
    const float4 v = *reinterpret_cast<const float4*>(in + i);
    union { bf16 b[4]; ushort4 u; } H, L;
    H.b[0] = (bf16)v.x; H.b[1] = (bf16)v.y; H.b[2] = (bf16)v.z; H.b[3] = (bf16)v.w;
    *reinterpret_cast<ushort4*>(hi + i) = H.u;
    if (lo) {
        L.b[0] = (bf16)(v.x - (float)H.b[0]);
        L.b[1] = (bf16)(v.y - (float)H.b[1]);
        L.b[2] = (bf16)(v.z - (float)H.b[2]);
        L.b[3] = (bf16)(v.w - (float)H.b[3]);
        *reinterpret_cast<ushort4*>(lo + i) = L.u;
    }
}

// row-wise causal softmax: P[row, 0..row] = softmax(S[row, 0..row]), zeros to
// the 128-padded row end (so the causal-K GEMM can read full 128-blocks).
__global__ __launch_bounds__(256) void softmax_rows(
    const float* __restrict__ S, bf16* __restrict__ P, int n)
{
    const int row = blockIdx.x;
    const int len = row + 1;
    const int padlen = ((row >> 7) + 1) << 7;
    const float* srow = S + (size_t)row * n;
    bf16* prow = P + (size_t)row * n;
    const int tid = threadIdx.x;
    const int lane = tid & 63, wave = tid >> 6;
    __shared__ float red[4];

    float m = -3.0e38f;
    for (int j = tid; j < len; j += 256) m = fmaxf(m, srow[j]);
    #pragma unroll
    for (int off = 32; off; off >>= 1) m = fmaxf(m, __shfl_xor(m, off, 64));
    if (lane == 0) red[wave] = m;
    __syncthreads();
    m = fmaxf(fmaxf(red[0], red[1]), fmaxf(red[2], red[3]));
    __syncthreads();

    float s = 0.f;
    for (int j = tid; j < len; j += 256) s += __expf(srow[j] - m);
    #pragma unroll
    for (int off = 32; off; off >>= 1) s += __shfl_xor(s, off, 64);
    if (lane == 0) red[wave] = s;
    __syncthreads();
    s = red[0] + red[1] + red[2] + red[3];
    const float inv = 1.0f / s;

    const bf16 z = (bf16)0.0f;
    for (int j = tid; j < padlen; j += 256)
        prow[j] = (j < len) ? (bf16)(__expf(srow[j] - m) * inv) : z;
}

// out[c*rows + r] = (bf16)in[r*cols + c]   (fp32 in, bf16 out)
__global__ __launch_bounds__(256) void transpose_f32_bf16(
    const float* __restrict__ in, bf16* __restrict__ out, int rows, int cols)
{
    __shared__ float tile[32][33];
    const int bx = blockIdx.x;  // col tile
    const int by = blockIdx.y;  // row tile
    const int tx = threadIdx.x & 31;
    const int ty = threadIdx.x >> 5;  // 0..7
    #pragma unroll
    for (int r = 0; r < 4; ++r)
        tile[ty + 8 * r][tx] = in[(size_t)(by * 32 + ty + 8 * r) * cols + bx * 32 + tx];
    __syncthreads();
    #pragma unroll
    for (int r = 0; r < 4; ++r)
        out[(size_t)(bx * 32 + ty + 8 * r) * rows + by * 32 + tx] =
            (bf16)tile[tx][ty + 8 * r];
}

extern "C" void kernel_launch(void* const* d_in, const int* in_sizes, int n_in,
                              void* d_out, int out_size, void* d_ws, size_t ws_size,
                              hipStream_t stream)
{
    const int n = 4096, d = 2048;
    const float* x   = (const float*)d_in[0];
    const float* Wqk = (const float*)d_in[1];
    const float* Wov = (const float*)d_in[2];
    float* out = (float*)d_out;

    char* ws = (char*)d_ws;
    const size_t MB = 1 << 20;
    bf16*  xhi  = (bf16*)(ws);              // 16 MB  (n x d)
    bf16*  xlo  = (bf16*)(ws + 16  * MB);   // 16 MB
    bf16*  Whi  = (bf16*)(ws + 32  * MB);   //  8 MB  (d x d)
    bf16*  Wlo  = (bf16*)(ws + 40  * MB);   //  8 MB
    bf16*  Wov_h= (bf16*)(ws + 48  * MB);   //  8 MB
    bf16*  xT   = (bf16*)(ws + 56  * MB);   // 16 MB  (d x n)
    bf16*  qhi  = (bf16*)(ws + 72  * MB);   // 16 MB  (n x d)
    bf16*  qlo  = (bf16*)(ws + 88  * MB);   // 16 MB
    float* S    = (float*)(ws + 104 * MB);  // 64 MB  (n x n)  -> peak 168 MB
    bf16*  P    = (bf16*)(ws);              // 32 MB  (n x n), reuses xhi+xlo (dead)
    bf16*  o    = (bf16*)(ws + 32  * MB);   // 16 MB  (n x d), reuses Whi+Wlo (dead)

    const dim3 blk(256);

    // input fp32 -> bf16 hi/lo
    split_fp32<<<dim3((n * d) / (256 * 4)), blk, 0, stream>>>(x,   xhi, xlo, (size_t)n * d);
    split_fp32<<<dim3((d * d) / (256 * 4)), blk, 0, stream>>>(Wqk, Whi, Wlo, (size_t)d * d);
    split_fp32<<<dim3((d * d) / (256 * 4)), blk, 0, stream>>>(Wov, Wov_h, nullptr, (size_t)d * d);
    transpose_f32_bf16<<<dim3(d / 32, n / 32), blk, 0, stream>>>(x, xT, n, d);

    // q = x @ Wqk^T in split precision (3-phase), output split hi/lo
    gemm_bt<1, true, false, false><<<dim3(d / BN, n / BM), blk, 0, stream>>>(
        xhi, xlo, Whi, Wlo, nullptr, qhi, qlo, n, d, d);

    // S = q @ x^T in split precision (3-phase), lower-triangular blocks, fp32
    gemm_bt<0, true, true, false><<<dim3(n / BN, n / BM), blk, 0, stream>>>(
        qhi, qlo, xhi, xlo, S, nullptr, nullptr, n, n, d);

    // P = causal row softmax(S), bf16, zero-padded to 128 boundary
    softmax_rows<<<dim3(n), blk, 0, stream>>>(S, P, n);

    // o = P @ x = P @ xT^T  (K limited causally per row-block), bf16
    gemm_bt<2, false, false, true><<<dim3(d / BN, n / BM), blk, 0, stream>>>(
        P, nullptr, xT, nullptr, nullptr, o, nullptr, n, d, n);

    // out = o @ Wov^T, fp32 to d_out
    gemm_bt<0, false, false, false><<<dim3(d / BN, n / BM), blk, 0, stream>>>(
        o, nullptr, Wov_h, nullptr, out, nullptr, nullptr, n, d, d);
}

// Round 4
// 573.049 us; speedup vs baseline: 1.2026x; 1.1433x over previous
//
#include <hip/hip_runtime.h>
#include <hip/hip_bf16.h>
#include <stdint.h>
#include <stddef.h>

using bf16 = __hip_bfloat16;
using frag_ab = __attribute__((ext_vector_type(8))) short;  // 8 bf16 (4 VGPRs)
using frag_cd = __attribute__((ext_vector_type(4))) float;  // 4 fp32 acc

constexpr int BM = 128, BN = 128, BK = 32;

// async global->LDS DMA, 16 B/lane; LDS dest = wave-uniform base + lane*16
#define GLOAD_LDS16(gp, lp)                                        \
    __builtin_amdgcn_global_load_lds(                              \
        (const __attribute__((address_space(1))) unsigned int*)(gp),\
        (__attribute__((address_space(3))) unsigned int*)(lp), 16, 0, 0)

// ---------------------------------------------------------------------------
// Split-precision GEMM: C = (Ahi+Alo) @ (Bhi+Blo)^T dropping the lo*lo term.
// Interleaved: per k0 stage loads all 4 tiles (32 KB LDS) and issues 48 MFMA
// per wave between one barrier pair (vs 16 for the 3-sequential-phase form).
// EPI: 0 = fp32 C, 1 = split bf16 hi/lo. CAUSAL: skip blocks with bx > by.
template <int EPI, bool CAUSAL>
__global__ __launch_bounds__(256) void gemm_bt_split3(
    const bf16* __restrict__ Ahi, const bf16* __restrict__ Alo,
    const bf16* __restrict__ Bhi, const bf16* __restrict__ Blo,
    float* __restrict__ Cf, bf16* __restrict__ Co, bf16* __restrict__ Clo,
    int M, int N, int K)
{
    const int bx = blockIdx.x;  // N tile
    const int by = blockIdx.y;  // M tile
    if (CAUSAL && bx > by) return;

    const int tid   = threadIdx.x;
    const int lane  = tid & 63;
    const int wave  = tid >> 6;
    const int wm    = wave >> 1;   // 0..1
    const int wn    = wave & 1;    // 0..1
    const int lrow  = lane & 15;
    const int lquad = lane >> 4;

    __shared__ bf16 sAh[BM * BK];  // 8 KB each, 32 KB total
    __shared__ bf16 sAl[BM * BK];
    __shared__ bf16 sBh[BN * BK];
    __shared__ bf16 sBl[BN * BK];

    const int row0 = by * BM;
    const int col0 = bx * BN;

    // staging: thread t, round r covers tile row (t>>2)+64r, cols (t&3)*8..+7
    const int srow = tid >> 2;
    const int scol = (tid & 3) * 8;
    const int lbase = wave * 512;  // wave-uniform LDS element base (+r*2048)

    frag_cd acc[4][4];
    const frag_cd fzero = {0.f, 0.f, 0.f, 0.f};
    #pragma unroll
    for (int i = 0; i < 4; ++i)
        #pragma unroll
        for (int j = 0; j < 4; ++j) acc[i][j] = fzero;

    for (int k0 = 0; k0 < K; k0 += BK) {
        __syncthreads();
        #pragma unroll
        for (int r = 0; r < 2; ++r) {
            const int trow = srow + 64 * r;
            const size_t ga = (size_t)(row0 + trow) * K + k0 + scol;
            const size_t gb = (size_t)(col0 + trow) * K + k0 + scol;
            const int ldst = lbase + r * 2048;
            GLOAD_LDS16(&Ahi[ga], &sAh[ldst]);
            GLOAD_LDS16(&Alo[ga], &sAl[ldst]);
            GLOAD_LDS16(&Bhi[gb], &sBh[ldst]);
            GLOAD_LDS16(&Blo[gb], &sBl[ldst]);
        }
        __syncthreads();

        frag_ab ah[4], al[4], bh[4], bl[4];
        #pragma unroll
        for (int mi = 0; mi < 4; ++mi) {
            const int off = (wm * 64 + mi * 16 + lrow) * BK + lquad * 8;
            ah[mi] = *reinterpret_cast<const frag_ab*>(&sAh[off]);
            al[mi] = *reinterpret_cast<const frag_ab*>(&sAl[off]);
        }
        #pragma unroll
        for (int ni = 0; ni < 4; ++ni) {
            const int off = (wn * 64 + ni * 16 + lrow) * BK + lquad * 8;
            bh[ni] = *reinterpret_cast<const frag_ab*>(&sBh[off]);
            bl[ni] = *reinterpret_cast<const frag_ab*>(&sBl[off]);
        }

        #pragma unroll
        for (int mi = 0; mi < 4; ++mi)
            #pragma unroll
            for (int ni = 0; ni < 4; ++ni) {
                acc[mi][ni] = __builtin_amdgcn_mfma_f32_16x16x32_bf16(
                    ah[mi], bh[ni], acc[mi][ni], 0, 0, 0);
                acc[mi][ni] = __builtin_amdgcn_mfma_f32_16x16x32_bf16(
                    al[mi], bh[ni], acc[mi][ni], 0, 0, 0);
                acc[mi][ni] = __builtin_amdgcn_mfma_f32_16x16x32_bf16(
                    ah[mi], bl[ni], acc[mi][ni], 0, 0, 0);
            }
    }

    #pragma unroll
    for (int mi = 0; mi < 4; ++mi) {
        #pragma unroll
        for (int ni = 0; ni < 4; ++ni) {
            #pragma unroll
            for (int r = 0; r < 4; ++r) {
                const int row = row0 + wm * 64 + mi * 16 + lquad * 4 + r;
                const int col = col0 + wn * 64 + ni * 16 + lrow;
                const size_t idx = (size_t)row * N + col;
                const float v = acc[mi][ni][r];
                if (EPI == 0) {
                    Cf[idx] = v;
                } else {
                    const bf16 h = (bf16)v;
                    Co[idx]  = h;
                    Clo[idx] = (bf16)(v - (float)h);
                }
            }
        }
    }
}

// ---------------------------------------------------------------------------
// Plain GEMM: C = A @ B^T (bf16 in). EPI: 0 = fp32 C, 2 = bf16 C.
// KCAUSAL: K-loop limited to (by+1)*BM (for attn@x where A rows are causal)
template <int EPI, bool KCAUSAL>
__global__ __launch_bounds__(256) void gemm_bt(
    const bf16* __restrict__ A, const bf16* __restrict__ B,
    float* __restrict__ Cf, bf16* __restrict__ Co,
    int M, int N, int K)
{
    const int bx = blockIdx.x;
    const int by = blockIdx.y;

    const int tid   = threadIdx.x;
    const int lane  = tid & 63;
    const int wave  = tid >> 6;
    const int wm    = wave >> 1;
    const int wn    = wave & 1;
    const int lrow  = lane & 15;
    const int lquad = lane >> 4;

    __shared__ bf16 sA[BM * BK];
    __shared__ bf16 sB[BN * BK];

    const int row0 = by * BM;
    const int col0 = bx * BN;

    const int srow = tid >> 2;
    const int scol = (tid & 3) * 8;
    const int lbase = wave * 512;

    frag_cd acc[4][4];
    const frag_cd fzero = {0.f, 0.f, 0.f, 0.f};
    #pragma unroll
    for (int i = 0; i < 4; ++i)
        #pragma unroll
        for (int j = 0; j < 4; ++j) acc[i][j] = fzero;

    const int Keff = KCAUSAL ? (by + 1) * BM : K;

    for (int k0 = 0; k0 < Keff; k0 += BK) {
        __syncthreads();
        #pragma unroll
        for (int r = 0; r < 2; ++r) {
            const int trow = srow + 64 * r;
            GLOAD_LDS16(&A[(size_t)(row0 + trow) * K + k0 + scol], &sA[lbase + r * 2048]);
            GLOAD_LDS16(&B[(size_t)(col0 + trow) * K + k0 + scol], &sB[lbase + r * 2048]);
        }
        __syncthreads();

        frag_ab av[4], bv[4];
        #pragma unroll
        for (int mi = 0; mi < 4; ++mi)
            av[mi] = *reinterpret_cast<const frag_ab*>(
                &sA[(wm * 64 + mi * 16 + lrow) * BK + lquad * 8]);
        #pragma unroll
        for (int ni = 0; ni < 4; ++ni)
            bv[ni] = *reinterpret_cast<const frag_ab*>(
                &sB[(wn * 64 + ni * 16 + lrow) * BK + lquad * 8]);

        #pragma unroll
        for (int mi = 0; mi < 4; ++mi)
            #pragma unroll
            for (int ni = 0; ni < 4; ++ni)
                acc[mi][ni] = __builtin_amdgcn_mfma_f32_16x16x32_bf16(
                    av[mi], bv[ni], acc[mi][ni], 0, 0, 0);
    }

    #pragma unroll
    for (int mi = 0; mi < 4; ++mi) {
        #pragma unroll
        for (int ni = 0; ni < 4; ++ni) {
            #pragma unroll
            for (int r = 0; r < 4; ++r) {
                const int row = row0 + wm * 64 + mi * 16 + lquad * 4 + r;
                const int col = col0 + wn * 64 + ni * 16 + lrow;
                const size_t idx = (size_t)row * N + col;
                const float v = acc[mi][ni][r];
                if (EPI == 0) Cf[idx] = v;
                else          Co[idx] = (bf16)v;
            }
        }
    }
}

// fp32 -> bf16 hi (+ optional lo residual), 4 elems/thread
__global__ __launch_bounds__(256) void split_fp32(
    const float* __restrict__ in, bf16* __restrict__ hi, bf16* __restrict__ lo,
    size_t nelem)
{
    const size_t i = ((size_t)blockIdx.x * 256 + threadIdx.x) * 4;
    if (i >= nelem) return;
    const float4 v = *reinterpret_cast<const float4*>(in + i);
    union { bf16 b[4]; ushort4 u; } H, L;
    H.b[0] = (bf16)v.x; H.b[1] = (bf16)v.y; H.b[2] = (bf16)v.z; H.b[3] = (bf16)v.w;
    *reinterpret_cast<ushort4*>(hi + i) = H.u;
    if (lo) {
        L.b[0] = (bf16)(v.x - (float)H.b[0]);
        L.b[1] = (bf16)(v.y - (float)H.b[1]);
        L.b[2] = (bf16)(v.z - (float)H.b[2]);
        L.b[3] = (bf16)(v.w - (float)H.b[3]);
        *reinterpret_cast<ushort4*>(lo + i) = L.u;
    }
}

// row-wise causal softmax, online max+sum (2 passes over S instead of 3);
// zero-pads P to the 128 boundary so the causal-K GEMM reads full blocks.
__global__ __launch_bounds__(256) void softmax_rows(
    const float* __restrict__ S, bf16* __restrict__ P, int n)
{
    const int row = blockIdx.x;
    const int len = row + 1;
    const int padlen = ((row >> 7) + 1) << 7;
    const float* srow = S + (size_t)row * n;
    bf16* prow = P + (size_t)row * n;
    const int tid = threadIdx.x;
    const int lane = tid & 63, wave = tid >> 6;
    __shared__ float redm[4], reds[4];

    float m = -3.0e38f, s = 0.f;
    for (int j = tid; j < len; j += 256) {
        const float v = srow[j];
        const float mn = fmaxf(m, v);
        s = s * __expf(m - mn) + __expf(v - mn);
        m = mn;
    }
    #pragma unroll
    for (int off = 32; off; off >>= 1) {
        const float mo = __shfl_xor(m, off, 64);
        const float so = __shfl_xor(s, off, 64);
        const float mn = fmaxf(m, mo);
        s = s * __expf(m - mn) + so * __expf(mo - mn);
        m = mn;
    }
    if (lane == 0) { redm[wave] = m; reds[wave] = s; }
    __syncthreads();
    float M = redm[0], Sm = reds[0];
    #pragma unroll
    for (int w = 1; w < 4; ++w) {
        const float mn = fmaxf(M, redm[w]);
        Sm = Sm * __expf(M - mn) + reds[w] * __expf(redm[w] - mn);
        M = mn;
    }
    const float inv = 1.0f / Sm;

    const bf16 z = (bf16)0.0f;
    for (int j = tid; j < padlen; j += 256)
        prow[j] = (j < len) ? (bf16)(__expf(srow[j] - M) * inv) : z;
}

// out[c*rows + r] = (bf16)in[r*cols + c]   (fp32 in, bf16 out)
__global__ __launch_bounds__(256) void transpose_f32_bf16(
    const float* __restrict__ in, bf16* __restrict__ out, int rows, int cols)
{
    __shared__ float tile[32][33];
    const int bx = blockIdx.x;
    const int by = blockIdx.y;
    const int tx = threadIdx.x & 31;
    const int ty = threadIdx.x >> 5;
    #pragma unroll
    for (int r = 0; r < 4; ++r)
        tile[ty + 8 * r][tx] = in[(size_t)(by * 32 + ty + 8 * r) * cols + bx * 32 + tx];
    __syncthreads();
    #pragma unroll
    for (int r = 0; r < 4; ++r)
        out[(size_t)(bx * 32 + ty + 8 * r) * rows + by * 32 + tx] =
            (bf16)tile[tx][ty + 8 * r];
}

extern "C" void kernel_launch(void* const* d_in, const int* in_sizes, int n_in,
                              void* d_out, int out_size, void* d_ws, size_t ws_size,
                              hipStream_t stream)
{
    const int n = 4096, d = 2048;
    const float* x   = (const float*)d_in[0];
    const float* Wqk = (const float*)d_in[1];
    const float* Wov = (const float*)d_in[2];
    float* out = (float*)d_out;

    char* ws = (char*)d_ws;
    const size_t MB = 1 << 20;
    bf16*  xhi  = (bf16*)(ws);              // 16 MB  (n x d)
    bf16*  xlo  = (bf16*)(ws + 16  * MB);   // 16 MB
    bf16*  Whi  = (bf16*)(ws + 32  * MB);   //  8 MB  (d x d)
    bf16*  Wlo  = (bf16*)(ws + 40  * MB);   //  8 MB
    bf16*  Wov_h= (bf16*)(ws + 48  * MB);   //  8 MB
    bf16*  xT   = (bf16*)(ws + 56  * MB);   // 16 MB  (d x n)
    bf16*  qhi  = (bf16*)(ws + 72  * MB);   // 16 MB  (n x d)
    bf16*  qlo  = (bf16*)(ws + 88  * MB);   // 16 MB
    float* S    = (float*)(ws + 104 * MB);  // 64 MB  (n x n)  -> peak 168 MB
    bf16*  P    = (bf16*)(ws);              // 32 MB  (n x n), reuses xhi+xlo (dead)
    bf16*  o    = (bf16*)(ws + 32  * MB);   // 16 MB  (n x d), reuses Whi+Wlo (dead)

    const dim3 blk(256);

    // input fp32 -> bf16 hi/lo
    split_fp32<<<dim3((n * d) / (256 * 4)), blk, 0, stream>>>(x,   xhi, xlo, (size_t)n * d);
    split_fp32<<<dim3((d * d) / (256 * 4)), blk, 0, stream>>>(Wqk, Whi, Wlo, (size_t)d * d);
    split_fp32<<<dim3((d * d) / (256 * 4)), blk, 0, stream>>>(Wov, Wov_h, nullptr, (size_t)d * d);
    transpose_f32_bf16<<<dim3(d / 32, n / 32), blk, 0, stream>>>(x, xT, n, d);

    // q = x @ Wqk^T, split precision (interleaved 3-product), output split hi/lo
    gemm_bt_split3<1, false><<<dim3(d / BN, n / BM), blk, 0, stream>>>(
        xhi, xlo, Whi, Wlo, nullptr, qhi, qlo, n, d, d);

    // S = q @ x^T, split precision (interleaved), lower-triangular blocks, fp32
    gemm_bt_split3<0, true><<<dim3(n / BN, n / BM), blk, 0, stream>>>(
        qhi, qlo, xhi, xlo, S, nullptr, nullptr, n, n, d);

    // P = causal row softmax(S), bf16, zero-padded to 128 boundary
    softmax_rows<<<dim3(n), blk, 0, stream>>>(S, P, n);

    // o = P @ x = P @ xT^T  (K limited causally per row-block), bf16
    gemm_bt<2, true><<<dim3(d / BN, n / BM), blk, 0, stream>>>(
        P, xT, nullptr, o, n, d, n);

    // out = o @ Wov^T, fp32 to d_out
    gemm_bt<0, false><<<dim3(d / BN, n / BM), blk, 0, stream>>>(
        o, Wov_h, out, nullptr, n, d, d);
}